// Round 9
// baseline (1171.841 us; speedup 1.0000x reference)
//
#include <hip/hip_runtime.h>

typedef unsigned short ushort_t;
typedef unsigned int uint_t;

typedef __attribute__((ext_vector_type(8))) __bf16 bf16x8_t;
typedef __attribute__((ext_vector_type(8))) short s16x8;
typedef __attribute__((ext_vector_type(4))) float f32x4;

#define T_TOK 2048
#define H_DIM 2048
#define I_DIM 1024
#define N_EXP 64
#define TOPK 8
#define MT 6         // 128-row m-tiles: covers up to 768 tokens/expert (mean 256)

#define BAR_RAW()  asm volatile("s_barrier" ::: "memory")
#define SCHED_FENCE() __builtin_amdgcn_sched_barrier(0)

#define LDS_OFF(p) ((uint_t)(unsigned long long)(p))

// global -> LDS DMA, 16B per lane, dest = ldsoff + lane*16 (linear); global src per-lane.
__device__ __forceinline__ void gl2lds(const void* g, uint_t ldsoff) {
  __builtin_amdgcn_global_load_lds(
      (const __attribute__((address_space(1))) unsigned*)(unsigned long long)(g),
      (__attribute__((address_space(3))) unsigned*)(ldsoff),
      16, 0, 0);
}

__device__ inline f32x4 mfma_bf16(s16x8 a, s16x8 b, f32x4 c) {
  return __builtin_amdgcn_mfma_f32_16x16x32_bf16(
      __builtin_bit_cast(bf16x8_t, a), __builtin_bit_cast(bf16x8_t, b), c, 0, 0, 0);
}

__device__ inline ushort_t f2bf(float f) {
  uint_t u = __float_as_uint(f);
  u += 0x7FFFu + ((u >> 16) & 1u);   // RNE
  return (ushort_t)(u >> 16);
}
__device__ inline float bf2f(ushort_t h) {
  return __uint_as_float(((uint_t)h) << 16);
}
__device__ inline uint_t pkbf(float a, float b) {
  uint_t r;
  asm("v_cvt_pk_bf16_f32 %0, %1, %2" : "=v"(r) : "v"(a), "v"(b));
  return r;
}
__device__ inline uint4 pk8v(f32x4 a, f32x4 b) {
  uint4 w;
  w.x = pkbf(a[0], a[1]); w.y = pkbf(a[2], a[3]);
  w.z = pkbf(b[0], b[1]); w.w = pkbf(b[2], b[3]);
  return w;
}

// ---------------- X fp32 -> bf16 pre-pass ----------------------------------------------
__global__ __launch_bounds__(256) void xcvt_kernel(const float* __restrict__ X,
                                                   ushort_t* __restrict__ Xbf) {
  int idx = (blockIdx.x * 256 + threadIdx.x) * 8;
  f32x4 a = *(const f32x4*)(X + idx);
  f32x4 b = *(const f32x4*)(X + idx + 4);
  *(uint4*)(Xbf + idx) = pk8v(a, b);
}

// ---------------- Router -------------------------------------------------------------
__global__ __launch_bounds__(256) void router_kernel(const float* __restrict__ X,
                                                     const float* __restrict__ GW,
                                                     float* __restrict__ logits) {
  __shared__ float xs[4][H_DIM];
  int tid = threadIdx.x;
  int t0 = blockIdx.x * 4;
  const float4* src = (const float4*)(X + (size_t)t0 * H_DIM);
  float4* dst = (float4*)(&xs[0][0]);
#pragma unroll
  for (int j = 0; j < 8; ++j) dst[tid + 256 * j] = src[tid + 256 * j];
  __syncthreads();
  int wave = tid >> 6, lane = tid & 63;
  int t = t0 + wave;
  const float4* w = (const float4*)(GW + (size_t)lane * H_DIM);
  const float4* xr = (const float4*)(&xs[wave][0]);
  float acc = 0.f;
  for (int i = 0; i < H_DIM / 4; ++i) {
    float4 a = xr[i];
    float4 b = w[i];
    acc = fmaf(a.x, b.x, acc);
    acc = fmaf(a.y, b.y, acc);
    acc = fmaf(a.z, b.z, acc);
    acc = fmaf(a.w, b.w, acc);
  }
  logits[(size_t)t * N_EXP + lane] = acc;
}

// ---------------- Softmax + top-8 ------------------------------------------------------
__global__ __launch_bounds__(256) void topk_kernel(const float* __restrict__ logits,
                                                   int* __restrict__ counts,
                                                   int* __restrict__ sel_e,
                                                   float* __restrict__ sel_w) {
  int tid = threadIdx.x;
  int wave = tid >> 6, lane = tid & 63;
  int t = blockIdx.x * 4 + wave;
  float l = logits[(size_t)t * N_EXP + lane];
  float m = l;
#pragma unroll
  for (int s = 32; s; s >>= 1) m = fmaxf(m, __shfl_xor(m, s, 64));
  float p = __expf(l - m);
  float sum = p;
#pragma unroll
  for (int s = 32; s; s >>= 1) sum += __shfl_xor(sum, s, 64);
  float prob = p / sum;

  float val = l;
#pragma unroll
  for (int k = 0; k < TOPK; ++k) {
    float bv = val;
    int bi = lane;
#pragma unroll
    for (int s = 32; s; s >>= 1) {
      float ov = __shfl_xor(bv, s, 64);
      int oi = __shfl_xor(bi, s, 64);
      if (ov > bv || (ov == bv && oi < bi)) { bv = ov; bi = oi; }
    }
    float bw = __shfl(prob, bi, 64);
    if (lane == 0) {
      sel_e[t * TOPK + k] = bi;
      sel_w[t * TOPK + k] = bw;
      atomicAdd(&counts[bi], 1);
    }
    if (lane == bi) val = -INFINITY;
  }
}

__global__ void scan_kernel(const int* __restrict__ counts, int* __restrict__ offsets,
                            int* __restrict__ cursor) {
  if (threadIdx.x == 0) {
    int acc = 0;
    for (int e = 0; e < N_EXP; ++e) { offsets[e] = acc; acc += counts[e]; }
    offsets[N_EXP] = acc;
  }
  if (threadIdx.x < N_EXP) cursor[threadIdx.x] = 0;
}

__global__ __launch_bounds__(256) void assign_kernel(const int* __restrict__ sel_e,
                                                     const float* __restrict__ sel_w,
                                                     const int* __restrict__ offsets,
                                                     int* __restrict__ cursor,
                                                     int* __restrict__ token_of,
                                                     float* __restrict__ weight_of) {
  int idx = blockIdx.x * 256 + threadIdx.x;
  int t = idx >> 3;
  int e = sel_e[idx];
  float w = sel_w[idx];
  int r = offsets[e] + atomicAdd(&cursor[e], 1);
  token_of[r] = t;
  weight_of[r] = w;
}

// =======================================================================================
// Shared GEMM machinery: 512 thr, tile 128(M)x128(N), BK=128, 8 waves (2M x 4N),
// per-wave 64x32 sub-tile, acc = 8 f32x4. A (bf16) via global_load_lds with
// XOR-swizzled source; B (fp32 weights) reg-staged 512B/row, converted on ds_write.
// LDS tiles: [128 rows][16 slots of 16B], phys_slot = logical_slot ^ (row&7).
// =======================================================================================

// ---------------- gate: g = X @ Wg^T (per expert), output bf16 (no activation) ---------
__global__ __launch_bounds__(512, 4) void gate_kernel(const ushort_t* __restrict__ Xbf,
                                                      const float* __restrict__ Wg,
                                                      const int* __restrict__ offsets,
                                                      const int* __restrict__ token_of,
                                                      ushort_t* __restrict__ gact) {
  int bid = blockIdx.x;
  int e = bid / (MT * 8);
  int mt = (bid % (MT * 8)) / 8;
  int nt = bid % 8;
  int base = offsets[e];
  int Me = offsets[e + 1] - base;
  if (mt * 128 >= Me) return;

  __shared__ ushort_t As[128 * 128];  // 32 KB
  __shared__ ushort_t Bs[128 * 128];  // 32 KB
  __shared__ int stok[128];

  int tid = threadIdx.x;
  if (tid < 128) {
    int gm = mt * 128 + tid;
    stok[tid] = token_of[base + (gm < Me ? gm : Me - 1)];
  }
  __syncthreads();

  int wave = tid >> 6, lane = tid & 63;
  int wm = wave >> 2, wn = wave & 3;

  // A DMA setup: 4 chunks/thread; chunk c = wave*4+d covers LDS rows 4c..4c+3.
  const char* aA[4];
  uint_t ldsoA[4];
#pragma unroll
  for (int d = 0; d < 4; ++d) {
    int c = wave * 4 + d;
    int r = 4 * c + (lane >> 4);
    int srcslot = (lane & 15) ^ (r & 7);
    aA[d] = (const char*)Xbf + (size_t)stok[r] * (H_DIM * 2) + srcslot * 16;
    ldsoA[d] = LDS_OFF(&As[0]) + c * 1024;
  }

  // B staging: 4 thr/row, thread covers floats [(tid&3)*32, +32)
  int br = tid >> 2, bq = tid & 3;
  const float* pB = Wg + ((size_t)e * I_DIM + nt * 128 + br) * H_DIM + bq * 32;

  f32x4 acc[4][2];
#pragma unroll
  for (int i = 0; i < 4; ++i)
#pragma unroll
    for (int j = 0; j < 2; ++j) acc[i][j] = (f32x4)0.f;

  f32x4 rB[8];
#pragma unroll
  for (int j = 0; j < 8; ++j) rB[j] = *(const f32x4*)(pB + 4 * j);

  int fr = lane & 15, q2 = lane >> 4;
  const int NK = H_DIM / 128;  // 16

  for (int k = 0; k < NK; ++k) {
    BAR_RAW();  // all waves done reading previous LDS tile
    // convert + write B(k); compiler inserts vmcnt wait for rB here
#pragma unroll
    for (int i = 0; i < 4; ++i) {
      int phys = (bq * 4 + i) ^ (br & 7);
      *(uint4*)&Bs[br * 128 + phys * 8] = pk8v(rB[2 * i], rB[2 * i + 1]);
    }
    SCHED_FENCE();
#pragma unroll
    for (int d = 0; d < 4; ++d) {
      gl2lds(aA[d], ldsoA[d]);
      aA[d] += 256;
    }
    SCHED_FENCE();
    if (k + 1 < NK) {
#pragma unroll
      for (int j = 0; j < 8; ++j) rB[j] = *(const f32x4*)(pB + (k + 1) * 128 + 4 * j);
      SCHED_FENCE();
      asm volatile("s_waitcnt vmcnt(8) lgkmcnt(0)\n\ts_barrier" ::: "memory");
    } else {
      asm volatile("s_waitcnt vmcnt(0) lgkmcnt(0)\n\ts_barrier" ::: "memory");
    }

    __builtin_amdgcn_s_setprio(1);
#pragma unroll
    for (int ks = 0; ks < 4; ++ks) {
      s16x8 af[4], bf[2];
#pragma unroll
      for (int mf = 0; mf < 4; ++mf) {
        int R = wm * 64 + mf * 16 + fr;
        af[mf] = *(const s16x8*)&As[R * 128 + (((ks * 4 + q2) ^ (R & 7)) * 8)];
      }
#pragma unroll
      for (int nf = 0; nf < 2; ++nf) {
        int R = wn * 32 + nf * 16 + fr;
        bf[nf] = *(const s16x8*)&Bs[R * 128 + (((ks * 4 + q2) ^ (R & 7)) * 8)];
      }
#pragma unroll
      for (int mf = 0; mf < 4; ++mf)
#pragma unroll
        for (int nf = 0; nf < 2; ++nf)
          acc[mf][nf] = mfma_bf16(af[mf], bf[nf], acc[mf][nf]);
    }
    __builtin_amdgcn_s_setprio(0);
  }

  // epilogue: write raw g (bf16)
#pragma unroll
  for (int mf = 0; mf < 4; ++mf)
#pragma unroll
    for (int nf = 0; nf < 2; ++nf) {
      f32x4 v = acc[mf][nf];
#pragma unroll
      for (int r = 0; r < 4; ++r) {
        int gm = mt * 128 + wm * 64 + mf * 16 + q2 * 4 + r;
        if (gm < Me) {
          int col = nt * 128 + wn * 32 + nf * 16 + fr;
          gact[(size_t)(base + gm) * I_DIM + col] = f2bf(v[r]);
        }
      }
    }
}

// ---------------- up: u = X @ Wu^T; combine act = silu(g)*u in place into gact ---------
__global__ __launch_bounds__(512, 4) void up_kernel(const ushort_t* __restrict__ Xbf,
                                                    const float* __restrict__ Wu,
                                                    const int* __restrict__ offsets,
                                                    const int* __restrict__ token_of,
                                                    ushort_t* __restrict__ gact) {
  int bid = blockIdx.x;
  int e = bid / (MT * 8);
  int mt = (bid % (MT * 8)) / 8;
  int nt = bid % 8;
  int base = offsets[e];
  int Me = offsets[e + 1] - base;
  if (mt * 128 >= Me) return;

  __shared__ ushort_t As[128 * 128];
  __shared__ ushort_t Bs[128 * 128];
  __shared__ int stok[128];

  int tid = threadIdx.x;
  if (tid < 128) {
    int gm = mt * 128 + tid;
    stok[tid] = token_of[base + (gm < Me ? gm : Me - 1)];
  }
  __syncthreads();

  int wave = tid >> 6, lane = tid & 63;
  int wm = wave >> 2, wn = wave & 3;

  const char* aA[4];
  uint_t ldsoA[4];
#pragma unroll
  for (int d = 0; d < 4; ++d) {
    int c = wave * 4 + d;
    int r = 4 * c + (lane >> 4);
    int srcslot = (lane & 15) ^ (r & 7);
    aA[d] = (const char*)Xbf + (size_t)stok[r] * (H_DIM * 2) + srcslot * 16;
    ldsoA[d] = LDS_OFF(&As[0]) + c * 1024;
  }

  int br = tid >> 2, bq = tid & 3;
  const float* pB = Wu + ((size_t)e * I_DIM + nt * 128 + br) * H_DIM + bq * 32;

  f32x4 acc[4][2];
#pragma unroll
  for (int i = 0; i < 4; ++i)
#pragma unroll
    for (int j = 0; j < 2; ++j) acc[i][j] = (f32x4)0.f;

  f32x4 rB[8];
#pragma unroll
  for (int j = 0; j < 8; ++j) rB[j] = *(const f32x4*)(pB + 4 * j);

  int fr = lane & 15, q2 = lane >> 4;
  const int NK = H_DIM / 128;

  for (int k = 0; k < NK; ++k) {
    BAR_RAW();
#pragma unroll
    for (int i = 0; i < 4; ++i) {
      int phys = (bq * 4 + i) ^ (br & 7);
      *(uint4*)&Bs[br * 128 + phys * 8] = pk8v(rB[2 * i], rB[2 * i + 1]);
    }
    SCHED_FENCE();
#pragma unroll
    for (int d = 0; d < 4; ++d) {
      gl2lds(aA[d], ldsoA[d]);
      aA[d] += 256;
    }
    SCHED_FENCE();
    if (k + 1 < NK) {
#pragma unroll
      for (int j = 0; j < 8; ++j) rB[j] = *(const f32x4*)(pB + (k + 1) * 128 + 4 * j);
      SCHED_FENCE();
      asm volatile("s_waitcnt vmcnt(8) lgkmcnt(0)\n\ts_barrier" ::: "memory");
    } else {
      asm volatile("s_waitcnt vmcnt(0) lgkmcnt(0)\n\ts_barrier" ::: "memory");
    }

    __builtin_amdgcn_s_setprio(1);
#pragma unroll
    for (int ks = 0; ks < 4; ++ks) {
      s16x8 af[4], bf[2];
#pragma unroll
      for (int mf = 0; mf < 4; ++mf) {
        int R = wm * 64 + mf * 16 + fr;
        af[mf] = *(const s16x8*)&As[R * 128 + (((ks * 4 + q2) ^ (R & 7)) * 8)];
      }
#pragma unroll
      for (int nf = 0; nf < 2; ++nf) {
        int R = wn * 32 + nf * 16 + fr;
        bf[nf] = *(const s16x8*)&Bs[R * 128 + (((ks * 4 + q2) ^ (R & 7)) * 8)];
      }
#pragma unroll
      for (int mf = 0; mf < 4; ++mf)
#pragma unroll
        for (int nf = 0; nf < 2; ++nf)
          acc[mf][nf] = mfma_bf16(af[mf], bf[nf], acc[mf][nf]);
    }
    __builtin_amdgcn_s_setprio(0);
  }

  // epilogue: act = silu(g) * u, in place over gact
#pragma unroll
  for (int mf = 0; mf < 4; ++mf)
#pragma unroll
    for (int nf = 0; nf < 2; ++nf) {
      f32x4 v = acc[mf][nf];
#pragma unroll
      for (int r = 0; r < 4; ++r) {
        int gm = mt * 128 + wm * 64 + mf * 16 + q2 * 4 + r;
        if (gm < Me) {
          int col = nt * 128 + wn * 32 + nf * 16 + fr;
          size_t off = (size_t)(base + gm) * I_DIM + col;
          float gv = bf2f(gact[off]);
          float s = gv / (1.f + __expf(-gv));
          gact[off] = f2bf(s * v[r]);
        }
      }
    }
}

// ---------------- down: out += w * (act @ Wd^T) ----------------------------------------
__global__ __launch_bounds__(512, 4) void down_kernel(const ushort_t* __restrict__ gact,
                                                      const float* __restrict__ Wd,
                                                      const int* __restrict__ offsets,
                                                      const int* __restrict__ token_of,
                                                      const float* __restrict__ weight_of,
                                                      float* __restrict__ out) {
  int bid = blockIdx.x;
  int e = bid / (MT * 16);
  int mt = (bid % (MT * 16)) / 16;
  int nt = bid % 16;
  int base = offsets[e];
  int Me = offsets[e + 1] - base;
  if (mt * 128 >= Me) return;

  __shared__ ushort_t As[128 * 128];
  __shared__ ushort_t Bs[128 * 128];
  __shared__ int stok[128];
  __shared__ float sw[128];

  int tid = threadIdx.x;
  if (tid < 128) {
    int gm = mt * 128 + tid;
    int ok = gm < Me;
    stok[tid] = token_of[base + (ok ? gm : Me - 1)];
    sw[tid] = ok ? weight_of[base + gm] : 0.f;
  }
  __syncthreads();

  int wave = tid >> 6, lane = tid & 63;
  int wm = wave >> 2, wn = wave & 3;

  const char* aA[4];
  uint_t ldsoA[4];
#pragma unroll
  for (int d = 0; d < 4; ++d) {
    int c = wave * 4 + d;
    int r = 4 * c + (lane >> 4);
    int gm = mt * 128 + r;
    if (gm >= Me) gm = Me - 1;
    int srcslot = (lane & 15) ^ (r & 7);
    aA[d] = (const char*)gact + (size_t)(base + gm) * (I_DIM * 2) + srcslot * 16;
    ldsoA[d] = LDS_OFF(&As[0]) + c * 1024;
  }

  int br = tid >> 2, bq = tid & 3;
  const float* pB = Wd + ((size_t)e * H_DIM + nt * 128 + br) * I_DIM + bq * 32;

  f32x4 acc[4][2];
#pragma unroll
  for (int i = 0; i < 4; ++i)
#pragma unroll
    for (int j = 0; j < 2; ++j) acc[i][j] = (f32x4)0.f;

  f32x4 rB[8];
#pragma unroll
  for (int j = 0; j < 8; ++j) rB[j] = *(const f32x4*)(pB + 4 * j);

  int fr = lane & 15, q2 = lane >> 4;
  const int NK = I_DIM / 128;  // 8

  for (int k = 0; k < NK; ++k) {
    BAR_RAW();
#pragma unroll
    for (int i = 0; i < 4; ++i) {
      int phys = (bq * 4 + i) ^ (br & 7);
      *(uint4*)&Bs[br * 128 + phys * 8] = pk8v(rB[2 * i], rB[2 * i + 1]);
    }
    SCHED_FENCE();
#pragma unroll
    for (int d = 0; d < 4; ++d) {
      gl2lds(aA[d], ldsoA[d]);
      aA[d] += 256;
    }
    SCHED_FENCE();
    if (k + 1 < NK) {
#pragma unroll
      for (int j = 0; j < 8; ++j) rB[j] = *(const f32x4*)(pB + (k + 1) * 128 + 4 * j);
      SCHED_FENCE();
      asm volatile("s_waitcnt vmcnt(8) lgkmcnt(0)\n\ts_barrier" ::: "memory");
    } else {
      asm volatile("s_waitcnt vmcnt(0) lgkmcnt(0)\n\ts_barrier" ::: "memory");
    }

    __builtin_amdgcn_s_setprio(1);
#pragma unroll
    for (int ks = 0; ks < 4; ++ks) {
      s16x8 af[4], bf[2];
#pragma unroll
      for (int mf = 0; mf < 4; ++mf) {
        int R = wm * 64 + mf * 16 + fr;
        af[mf] = *(const s16x8*)&As[R * 128 + (((ks * 4 + q2) ^ (R & 7)) * 8)];
      }
#pragma unroll
      for (int nf = 0; nf < 2; ++nf) {
        int R = wn * 32 + nf * 16 + fr;
        bf[nf] = *(const s16x8*)&Bs[R * 128 + (((ks * 4 + q2) ^ (R & 7)) * 8)];
      }
#pragma unroll
      for (int mf = 0; mf < 4; ++mf)
#pragma unroll
        for (int nf = 0; nf < 2; ++nf)
          acc[mf][nf] = mfma_bf16(af[mf], bf[nf], acc[mf][nf]);
    }
    __builtin_amdgcn_s_setprio(0);
  }

#pragma unroll
  for (int mf = 0; mf < 4; ++mf)
#pragma unroll
    for (int nf = 0; nf < 2; ++nf) {
      f32x4 v = acc[mf][nf];
#pragma unroll
      for (int r = 0; r < 4; ++r) {
        int mloc = wm * 64 + mf * 16 + q2 * 4 + r;
        int gm = mt * 128 + mloc;
        if (gm < Me) {
          int t = stok[mloc];
          float w = sw[mloc];
          int h = nt * 128 + wn * 32 + nf * 16 + fr;
          unsafeAtomicAdd(&out[(size_t)t * H_DIM + h], w * v[r]);
        }
      }
    }
}

// ---------------------------------------------------------------------------------------
extern "C" void kernel_launch(void* const* d_in, const int* in_sizes, int n_in,
                              void* d_out, int out_size, void* d_ws, size_t ws_size,
                              hipStream_t stream) {
  const float* X = (const float*)d_in[0];
  const float* GW = (const float*)d_in[1];
  const float* Wg = (const float*)d_in[2];
  const float* Wu = (const float*)d_in[3];
  const float* Wd = (const float*)d_in[4];
  float* out = (float*)d_out;
  float* logits = out + (size_t)T_TOK * H_DIM;

  char* ws = (char*)d_ws;
  int* counts = (int*)ws;                          // 256 B
  int* cursor = (int*)(ws + 256);                  // 256 B
  int* offsets = (int*)(ws + 512);                 // 260 B
  int* sel_e = (int*)(ws + 1024);                  // 64 KB
  float* sel_w = (float*)(ws + 1024 + 65536);      // 64 KB
  int* token_of = (int*)(ws + 1024 + 2 * 65536);
  float* weight_of = (float*)(ws + 1024 + 3 * 65536);
  ushort_t* Xbf = (ushort_t*)(ws + 524288);        // 8 MB
  ushort_t* gact = (ushort_t*)(ws + 524288 + 8388608);  // 32 MB

  hipMemsetAsync(out, 0, (size_t)T_TOK * H_DIM * sizeof(float), stream);
  hipMemsetAsync(ws, 0, 1024, stream);

  xcvt_kernel<<<(T_TOK * H_DIM) / (256 * 8), 256, 0, stream>>>(X, Xbf);
  router_kernel<<<T_TOK / 4, 256, 0, stream>>>(X, GW, logits);
  topk_kernel<<<T_TOK / 4, 256, 0, stream>>>(logits, counts, sel_e, sel_w);
  scan_kernel<<<1, 64, 0, stream>>>(counts, offsets, cursor);
  assign_kernel<<<(T_TOK * TOPK) / 256, 256, 0, stream>>>(sel_e, sel_w, offsets, cursor,
                                                          token_of, weight_of);
  gate_kernel<<<N_EXP * MT * 8, 512, 0, stream>>>(Xbf, Wg, offsets, token_of, gact);
  up_kernel<<<N_EXP * MT * 8, 512, 0, stream>>>(Xbf, Wu, offsets, token_of, gact);
  down_kernel<<<N_EXP * MT * 16, 512, 0, stream>>>(gact, Wd, offsets, token_of,
                                                   weight_of, out);
}

// Round 10
// 832.195 us; speedup vs baseline: 1.4081x; 1.4081x over previous
//
#include <hip/hip_runtime.h>

typedef unsigned short ushort_t;
typedef unsigned int uint_t;

typedef __attribute__((ext_vector_type(8))) __bf16 bf16x8_t;
typedef __attribute__((ext_vector_type(8))) short s16x8;
typedef __attribute__((ext_vector_type(4))) float f32x4;

#define T_TOK 2048
#define H_DIM 2048
#define I_DIM 1024
#define N_EXP 64
#define TOPK 8
#define MT 6         // 128-row m-tiles: covers up to 768 tokens/expert (mean 256)
#define LSTR 40      // LDS row stride in bf16 elems (BK=32 + 8 pad) — R4-proven

// Raw barrier: does NOT drain vmcnt -> in-flight global loads stay outstanding.
#define BAR_RAW()  asm volatile("s_barrier" ::: "memory")
// LDS-visibility barrier: drain ds ops (lgkm) then barrier; vmcnt untouched.
#define BAR_LGKM() asm volatile("s_waitcnt lgkmcnt(0)\n\ts_barrier" ::: "memory")

__device__ inline f32x4 mfma_bf16(s16x8 a, s16x8 b, f32x4 c) {
  return __builtin_amdgcn_mfma_f32_16x16x32_bf16(
      __builtin_bit_cast(bf16x8_t, a), __builtin_bit_cast(bf16x8_t, b), c, 0, 0, 0);
}

__device__ inline ushort_t f2bf(float f) {
  uint_t u = __float_as_uint(f);
  u += 0x7FFFu + ((u >> 16) & 1u);   // round-to-nearest-even
  return (ushort_t)(u >> 16);
}

// packed f32x2 -> bf16x2 (RNE), 1 instruction
__device__ inline uint_t pkbf(float a, float b) {
  uint_t r;
  asm("v_cvt_pk_bf16_f32 %0, %1, %2" : "=v"(r) : "v"(a), "v"(b));
  return r;
}
// float4 -> 4 bf16 (8 B)
__device__ inline uint2 pk4(float4 v) {
  uint2 w;
  w.x = pkbf(v.x, v.y);
  w.y = pkbf(v.z, v.w);
  return w;
}

// XCD-chunk swizzle (bijective when nwg % 8 == 0): HW round-robins orig bid over
// 8 XCDs; logical = (bid%8)*(nwg/8) + bid/8 gives each XCD a contiguous chunk.
__device__ __forceinline__ int xcd_swizzle(int bid, int nwg) {
  int q = nwg >> 3;
  return (bid & 7) * q + (bid >> 3);
}

// ---------------- Router: logits[t][e] = sum_h x[t][h] * gw[e][h] (fp32 exact) ----------
__global__ __launch_bounds__(256) void router_kernel(const float* __restrict__ X,
                                                     const float* __restrict__ GW,
                                                     float* __restrict__ logits) {
  __shared__ float xs[4][H_DIM];
  int tid = threadIdx.x;
  int t0 = blockIdx.x * 4;
  const float4* src = (const float4*)(X + (size_t)t0 * H_DIM);
  float4* dst = (float4*)(&xs[0][0]);
#pragma unroll
  for (int j = 0; j < 8; ++j) dst[tid + 256 * j] = src[tid + 256 * j];
  __syncthreads();
  int wave = tid >> 6, lane = tid & 63;
  int t = t0 + wave;
  const float4* w = (const float4*)(GW + (size_t)lane * H_DIM);
  const float4* xr = (const float4*)(&xs[wave][0]);
  float acc = 0.f;
  for (int i = 0; i < H_DIM / 4; ++i) {
    float4 a = xr[i];
    float4 b = w[i];
    acc = fmaf(a.x, b.x, acc);
    acc = fmaf(a.y, b.y, acc);
    acc = fmaf(a.z, b.z, acc);
    acc = fmaf(a.w, b.w, acc);
  }
  logits[(size_t)t * N_EXP + lane] = acc;
}

// ---------------- Softmax + top-8 per token (one wave per token) -----------------------
__global__ __launch_bounds__(256) void topk_kernel(const float* __restrict__ logits,
                                                   int* __restrict__ counts,
                                                   int* __restrict__ sel_e,
                                                   float* __restrict__ sel_w) {
  int tid = threadIdx.x;
  int wave = tid >> 6, lane = tid & 63;
  int t = blockIdx.x * 4 + wave;
  float l = logits[(size_t)t * N_EXP + lane];
  float m = l;
#pragma unroll
  for (int s = 32; s; s >>= 1) m = fmaxf(m, __shfl_xor(m, s, 64));
  float p = __expf(l - m);
  float sum = p;
#pragma unroll
  for (int s = 32; s; s >>= 1) sum += __shfl_xor(sum, s, 64);
  float prob = p / sum;

  float val = l;
#pragma unroll
  for (int k = 0; k < TOPK; ++k) {
    float bv = val;
    int bi = lane;
#pragma unroll
    for (int s = 32; s; s >>= 1) {
      float ov = __shfl_xor(bv, s, 64);
      int oi = __shfl_xor(bi, s, 64);
      if (ov > bv || (ov == bv && oi < bi)) { bv = ov; bi = oi; }
    }
    float bw = __shfl(prob, bi, 64);
    if (lane == 0) {
      sel_e[t * TOPK + k] = bi;
      sel_w[t * TOPK + k] = bw;
      atomicAdd(&counts[bi], 1);
    }
    if (lane == bi) val = -INFINITY;
  }
}

// ---------------- Prefix sum over 64 expert counts -------------------------------------
__global__ void scan_kernel(const int* __restrict__ counts, int* __restrict__ offsets,
                            int* __restrict__ cursor) {
  if (threadIdx.x == 0) {
    int acc = 0;
    for (int e = 0; e < N_EXP; ++e) { offsets[e] = acc; acc += counts[e]; }
    offsets[N_EXP] = acc;
  }
  if (threadIdx.x < N_EXP) cursor[threadIdx.x] = 0;
}

// ---------------- Assign packed rows ---------------------------------------------------
__global__ __launch_bounds__(256) void assign_kernel(const int* __restrict__ sel_e,
                                                     const float* __restrict__ sel_w,
                                                     const int* __restrict__ offsets,
                                                     int* __restrict__ cursor,
                                                     int* __restrict__ token_of,
                                                     float* __restrict__ weight_of) {
  int idx = blockIdx.x * 256 + threadIdx.x;  // 0..16383
  int t = idx >> 3;
  int e = sel_e[idx];
  float w = sel_w[idx];
  int r = offsets[e] + atomicAdd(&cursor[e], 1);
  token_of[r] = t;
  weight_of[r] = w;
}

// ---------------- Fused gate+up GEMM + SiLU -> act (bf16) ------------------------------
// 512 threads, block tile 128(M)x128(N) x2 projections, BK=32.
// 8 waves (2M x 4N), each wave owns 64x32 per projection: acc = 16 f32x4.
// launch_bounds (512,3): cap ~170 regs -> NO spill (R8's (512,4)=128 cap spilled),
// 3 waves/SIMD = 12 waves/CU.
__global__ __launch_bounds__(512, 3) void gateup_kernel(const float* __restrict__ X,
                                                        const float* __restrict__ Wg,
                                                        const float* __restrict__ Wu,
                                                        const int* __restrict__ offsets,
                                                        const int* __restrict__ token_of,
                                                        ushort_t* __restrict__ act) {
  int bid = xcd_swizzle(blockIdx.x, N_EXP * MT * 8);
  int e = bid / (MT * 8);
  int mt = (bid % (MT * 8)) / 8;
  int nt = bid % 8;
  int base = offsets[e];
  int Me = offsets[e + 1] - base;
  if (mt * 128 >= Me) return;

  __shared__ ushort_t As[128 * LSTR];   // 10 KB
  __shared__ ushort_t Bgs[128 * LSTR];  // 10 KB
  __shared__ ushort_t Bus[128 * LSTR];  // 10 KB
  __shared__ int stok[128];

  int tid = threadIdx.x;
  if (tid < 128) {
    int gm = mt * 128 + tid;
    int cm = gm < Me ? gm : (Me - 1);
    stok[tid] = token_of[base + cm];
  }
  __syncthreads();

  int wave = tid >> 6, lane = tid & 63;
  int wm = wave >> 2, wn = wave & 3;

  // Staging: 4 thr/row x 128 rows; each thread 8 floats (2 float4) at col (tid&3)*8.
  // One wave instruction = 16 rows x 128 B contiguous runs.
  int sr = tid >> 2, sc = (tid & 3) * 8;
  const float* pA = X + (size_t)stok[sr] * H_DIM + sc;
  const float* pG = Wg + ((size_t)e * I_DIM + nt * 128 + sr) * H_DIM + sc;
  const float* pU = Wu + ((size_t)e * I_DIM + nt * 128 + sr) * H_DIM + sc;

  f32x4 accg[4][2], accu[4][2];
#pragma unroll
  for (int i = 0; i < 4; ++i)
#pragma unroll
    for (int j = 0; j < 2; ++j) { accg[i][j] = (f32x4)0.f; accu[i][j] = (f32x4)0.f; }

  float4 rA[2], rG[2], rU[2];
  // prologue: tile 0 -> regs
#pragma unroll
  for (int j = 0; j < 2; ++j) {
    rA[j] = *(const float4*)(pA + 4 * j);
    rG[j] = *(const float4*)(pG + 4 * j);
    rU[j] = *(const float4*)(pU + 4 * j);
  }

  int fr = lane & 15, q2 = lane >> 4;

  for (int k0 = 0; k0 < H_DIM; k0 += 32) {
    BAR_RAW();  // all waves done reading prev tile; prefetch loads cross freely
    *(uint2*)&As[sr * LSTR + sc] = pk4(rA[0]);
    *(uint2*)&As[sr * LSTR + sc + 4] = pk4(rA[1]);
    *(uint2*)&Bgs[sr * LSTR + sc] = pk4(rG[0]);
    *(uint2*)&Bgs[sr * LSTR + sc + 4] = pk4(rG[1]);
    *(uint2*)&Bus[sr * LSTR + sc] = pk4(rU[0]);
    *(uint2*)&Bus[sr * LSTR + sc + 4] = pk4(rU[1]);
    if (k0 + 32 < H_DIM) {
      int kn = k0 + 32;
#pragma unroll
      for (int j = 0; j < 2; ++j) {
        rA[j] = *(const float4*)(pA + kn + 4 * j);
        rG[j] = *(const float4*)(pG + kn + 4 * j);
        rU[j] = *(const float4*)(pU + kn + 4 * j);
      }
    }
    BAR_LGKM();  // ds_writes visible; vmcnt untouched (prefetch in flight)

    s16x8 af[4], bg[2], bu[2];
#pragma unroll
    for (int mf = 0; mf < 4; ++mf)
      af[mf] = *(const s16x8*)&As[(wm * 64 + mf * 16 + fr) * LSTR + q2 * 8];
#pragma unroll
    for (int nf = 0; nf < 2; ++nf) {
      bg[nf] = *(const s16x8*)&Bgs[(wn * 32 + nf * 16 + fr) * LSTR + q2 * 8];
      bu[nf] = *(const s16x8*)&Bus[(wn * 32 + nf * 16 + fr) * LSTR + q2 * 8];
    }
    __builtin_amdgcn_s_setprio(1);
#pragma unroll
    for (int mf = 0; mf < 4; ++mf)
#pragma unroll
      for (int nf = 0; nf < 2; ++nf) {
        accg[mf][nf] = mfma_bf16(af[mf], bg[nf], accg[mf][nf]);
        accu[mf][nf] = mfma_bf16(af[mf], bu[nf], accu[mf][nf]);
      }
    __builtin_amdgcn_s_setprio(0);
  }

  // epilogue: act = silu(g)*u -> bf16
#pragma unroll
  for (int mf = 0; mf < 4; ++mf)
#pragma unroll
    for (int nf = 0; nf < 2; ++nf) {
      f32x4 g = accg[mf][nf], u = accu[mf][nf];
#pragma unroll
      for (int r = 0; r < 4; ++r) {
        int mloc = wm * 64 + mf * 16 + q2 * 4 + r;
        int gm = mt * 128 + mloc;
        if (gm < Me) {
          float gv = g[r], uv = u[r];
          float s = gv / (1.f + __expf(-gv));
          int col = nt * 128 + wn * 32 + nf * 16 + fr;
          act[(size_t)(base + gm) * I_DIM + col] = f2bf(s * uv);
        }
      }
    }
}

// ---------------- Down GEMM + weighted scatter to out ----------------------------------
// 512 threads, block tile 128(M)x128(N), BK=32; 8 waves (2Mx4N), each 64x32.
// acc = 8 f32x4; ~95 regs total -> (512,4) fits without spill.
__global__ __launch_bounds__(512, 4) void down_kernel(const ushort_t* __restrict__ act,
                                                      const float* __restrict__ Wd,
                                                      const int* __restrict__ offsets,
                                                      const int* __restrict__ token_of,
                                                      const float* __restrict__ weight_of,
                                                      float* __restrict__ out) {
  int bid = xcd_swizzle(blockIdx.x, N_EXP * MT * 16);
  int e = bid / (MT * 16);
  int mt = (bid % (MT * 16)) / 16;
  int nt = bid % 16;
  int base = offsets[e];
  int Me = offsets[e + 1] - base;
  if (mt * 128 >= Me) return;

  __shared__ ushort_t As[128 * LSTR];   // 10 KB
  __shared__ ushort_t Bs[128 * LSTR];   // 10 KB
  __shared__ int stok[128];
  __shared__ float sw[128];

  int tid = threadIdx.x;
  if (tid < 128) {
    int gm = mt * 128 + tid;
    int ok = gm < Me;
    int cm = ok ? gm : (Me - 1);
    stok[tid] = token_of[base + cm];
    sw[tid] = ok ? weight_of[base + gm] : 0.f;
  }
  __syncthreads();

  int wave = tid >> 6, lane = tid & 63;
  int wm = wave >> 2, wn = wave & 3;

  // A (act, bf16): 4 thr/row x 128 rows, 16 B each -> 16 rows x 64 B runs per wave instr
  int sr = tid >> 2;
  int ac = (tid & 3) * 8;     // bf16 col
  int r0 = mt * 128 + sr;
  if (r0 >= Me) r0 = Me - 1;
  const ushort_t* pA = act + (size_t)(base + r0) * I_DIM + ac;
  // B (Wd, fp32): 4 thr/row x 128 rows, each 8 floats -> 16 rows x 128 B runs
  int bc = (tid & 3) * 8;
  const float* pB = Wd + ((size_t)e * H_DIM + nt * 128 + sr) * I_DIM + bc;

  f32x4 acc[4][2];
#pragma unroll
  for (int i = 0; i < 4; ++i)
#pragma unroll
    for (int j = 0; j < 2; ++j) acc[i][j] = (f32x4)0.f;

  s16x8 rA;
  float4 rB[2];
  rA = *(const s16x8*)pA;
#pragma unroll
  for (int j = 0; j < 2; ++j) rB[j] = *(const float4*)(pB + 4 * j);

  int fr = lane & 15, q2 = lane >> 4;

  for (int k0 = 0; k0 < I_DIM; k0 += 32) {
    BAR_RAW();
    *(s16x8*)&As[sr * LSTR + ac] = rA;
    *(uint2*)&Bs[sr * LSTR + bc] = pk4(rB[0]);
    *(uint2*)&Bs[sr * LSTR + bc + 4] = pk4(rB[1]);
    if (k0 + 32 < I_DIM) {
      int kn = k0 + 32;
      rA = *(const s16x8*)(pA + kn);
#pragma unroll
      for (int j = 0; j < 2; ++j) rB[j] = *(const float4*)(pB + kn + 4 * j);
    }
    BAR_LGKM();

    s16x8 af[4], bf[2];
#pragma unroll
    for (int mf = 0; mf < 4; ++mf)
      af[mf] = *(const s16x8*)&As[(wm * 64 + mf * 16 + fr) * LSTR + q2 * 8];
#pragma unroll
    for (int nf = 0; nf < 2; ++nf)
      bf[nf] = *(const s16x8*)&Bs[(wn * 32 + nf * 16 + fr) * LSTR + q2 * 8];
    __builtin_amdgcn_s_setprio(1);
#pragma unroll
    for (int mf = 0; mf < 4; ++mf)
#pragma unroll
      for (int nf = 0; nf < 2; ++nf)
        acc[mf][nf] = mfma_bf16(af[mf], bf[nf], acc[mf][nf]);
    __builtin_amdgcn_s_setprio(0);
  }

#pragma unroll
  for (int mf = 0; mf < 4; ++mf)
#pragma unroll
    for (int nf = 0; nf < 2; ++nf) {
      f32x4 v = acc[mf][nf];
#pragma unroll
      for (int r = 0; r < 4; ++r) {
        int mloc = wm * 64 + mf * 16 + q2 * 4 + r;
        int gm = mt * 128 + mloc;
        if (gm < Me) {
          int t = stok[mloc];
          float w = sw[mloc];
          int h = nt * 128 + wn * 32 + nf * 16 + fr;
          unsafeAtomicAdd(&out[(size_t)t * H_DIM + h], w * v[r]);
        }
      }
    }
}

// ---------------------------------------------------------------------------------------
extern "C" void kernel_launch(void* const* d_in, const int* in_sizes, int n_in,
                              void* d_out, int out_size, void* d_ws, size_t ws_size,
                              hipStream_t stream) {
  const float* X = (const float*)d_in[0];
  const float* GW = (const float*)d_in[1];
  const float* Wg = (const float*)d_in[2];
  const float* Wu = (const float*)d_in[3];
  const float* Wd = (const float*)d_in[4];
  float* out = (float*)d_out;
  float* logits = out + (size_t)T_TOK * H_DIM;

  char* ws = (char*)d_ws;
  int* counts = (int*)ws;                       // 256 B
  int* cursor = (int*)(ws + 256);               // 256 B
  int* offsets = (int*)(ws + 512);              // 260 B
  int* sel_e = (int*)(ws + 1024);               // 64 KB
  float* sel_w = (float*)(ws + 1024 + 65536);   // 64 KB
  int* token_of = (int*)(ws + 1024 + 2 * 65536);
  float* weight_of = (float*)(ws + 1024 + 3 * 65536);
  ushort_t* act = (ushort_t*)(ws + 524288);     // 16384*1024*2 = 32 MB

  hipMemsetAsync(out, 0, (size_t)T_TOK * H_DIM * sizeof(float), stream);
  hipMemsetAsync(ws, 0, 1024, stream);

  router_kernel<<<T_TOK / 4, 256, 0, stream>>>(X, GW, logits);
  topk_kernel<<<T_TOK / 4, 256, 0, stream>>>(logits, counts, sel_e, sel_w);
  scan_kernel<<<1, 64, 0, stream>>>(counts, offsets, cursor);
  assign_kernel<<<(T_TOK * TOPK) / 256, 256, 0, stream>>>(sel_e, sel_w, offsets, cursor,
                                                          token_of, weight_of);
  gateup_kernel<<<N_EXP * MT * 8, 512, 0, stream>>>(X, Wg, Wu, offsets, token_of, act);
  down_kernel<<<N_EXP * MT * 16, 512, 0, stream>>>(act, Wd, offsets, token_of,
                                                   weight_of, out);
}